// Round 8
// baseline (1928.420 us; speedup 1.0000x reference)
//
#include <hip/hip_runtime.h>
#include <hip/hip_bf16.h>

#define DEV __device__ __forceinline__

using bf16 = __hip_bfloat16;
typedef __attribute__((ext_vector_type(8))) short short8v;  // 8 bf16 = 4 VGPRs
typedef __attribute__((ext_vector_type(4))) float f32x4;

constexpr int Bq = 16, Tq = 1024, Eq = 1024, Gq = 4, Nq = 8, Dq = 128, Vq = 2048;
constexpr int M1 = Bq * Tq;        // 16384
constexpr int N1q = Gq * Nq * Dq;  // 4096
constexpr int K1 = Eq;             // 1024
constexpr int K2 = Nq * Dq;        // 1024
constexpr int N2 = Vq;             // 2048

DEV unsigned short bfu(float x) {
  union { bf16 h; unsigned short u; } cv;
  cv.h = __float2bfloat16(x);
  return cv.u;
}

DEV float rcp_(float x) { return __builtin_amdgcn_rcpf(x); }
DEV float sigm(float x) { return rcp_(1.0f + __expf(-x)); }
DEV float tanh_(float x) { return fmaf(2.0f, rcp_(1.0f + __expf(-2.0f * x)), -1.0f); }

// async global->LDS, 16B per lane; LDS dest is wave-uniform base + lane*16
#define GLD16(gp, lp)                                                       \
  __builtin_amdgcn_global_load_lds(                                        \
      (const __attribute__((address_space(1))) void*)(gp),                 \
      (__attribute__((address_space(3))) void*)(lp), 16, 0, 0)

// ---------------------------------------------------------------------------
// Prep kernels: casts + transpose-cast
// ---------------------------------------------------------------------------
__global__ __launch_bounds__(256) void cast_f32_bf16(const float* __restrict__ s,
                                                     bf16* __restrict__ d, int n4) {
  const int i = blockIdx.x * 256 + threadIdx.x;
  if (i >= n4) return;
  const float4 v = ((const float4*)s)[i];
  ushort4 u;
  u.x = bfu(v.x); u.y = bfu(v.y); u.z = bfu(v.z); u.w = bfu(v.w);
  ((ushort4*)d)[i] = u;
}

// s: [SK][SN] f32 row-major  ->  d: [SN][SK] bf16 row-major
__global__ __launch_bounds__(256) void transpose_cast(const float* __restrict__ s,
                                                      bf16* __restrict__ d,
                                                      int SK, int SN) {
  __shared__ float t[32][33];
  const int n0 = blockIdx.x * 32, k0 = blockIdx.y * 32;
  const int tx = threadIdx.x & 31, ty = threadIdx.x >> 5;  // ty: 0..7
#pragma unroll
  for (int i = 0; i < 32; i += 8)
    t[ty + i][tx] = s[(size_t)(k0 + ty + i) * SN + n0 + tx];
  __syncthreads();
#pragma unroll
  for (int i = 0; i < 32; i += 8)
    d[(size_t)(n0 + ty + i) * SK + k0 + tx] = __float2bfloat16(t[tx][ty + i]);
}

// ---------------------------------------------------------------------------
// bf16 MFMA GEMM, m97 structure: C[M,N] = A[M,K] @ Bt[N,K]^T
// MODE 0: f32 out + bias.  MODE 2: bf16 out scattered to Wx_rec[b,n,t,d,g].
// ---------------------------------------------------------------------------
template <int MODE>
__global__ __launch_bounds__(256) void gemm_bt(const bf16* __restrict__ A,
                                               const bf16* __restrict__ Bt,
                                               void* __restrict__ Cout,
                                               const float* __restrict__ bp,
                                               int K, int N) {
  __shared__ bf16 As[128 * 32];
  __shared__ bf16 Bs[128 * 32];
  const int m0 = blockIdx.y * 128, n0 = blockIdx.x * 128;
  const int tid = threadIdx.x;
  const int lane = tid & 63, w = tid >> 6;
  const int wm = w >> 1, wn = w & 1;

  const int srow = lane >> 2, scol = (lane & 3) * 8;
  const int ca = w * 2;
  const bf16* Ag0 = A + (size_t)(m0 + ca * 16 + srow) * K + scol;
  const bf16* Ag1 = Ag0 + (size_t)16 * K;
  const bf16* Bg0 = Bt + (size_t)(n0 + ca * 16 + srow) * K + scol;
  const bf16* Bg1 = Bg0 + (size_t)16 * K;
  bf16* Al0 = As + ca * 512;
  bf16* Al1 = Al0 + 512;
  bf16* Bl0 = Bs + ca * 512;
  bf16* Bl1 = Bl0 + 512;

  f32x4 acc[4][4] = {};

  const int rr = lane & 15;
  const int kb = (lane >> 4) * 8;

  for (int k0 = 0; k0 < K; k0 += 32) {
    GLD16(Ag0 + k0, Al0);
    GLD16(Ag1 + k0, Al1);
    GLD16(Bg0 + k0, Bl0);
    GLD16(Bg1 + k0, Bl1);
    __syncthreads();
    short8v af[4], bfr[4];
#pragma unroll
    for (int i = 0; i < 4; ++i) {
      af[i]  = *(const short8v*)&As[(wm * 64 + i * 16 + rr) * 32 + kb];
      bfr[i] = *(const short8v*)&Bs[(wn * 64 + i * 16 + rr) * 32 + kb];
    }
#pragma unroll
    for (int i = 0; i < 4; ++i)
#pragma unroll
      for (int j = 0; j < 4; ++j)
        acc[i][j] = __builtin_amdgcn_mfma_f32_16x16x32_bf16(af[i], bfr[j], acc[i][j], 0, 0, 0);
    __syncthreads();
  }

  const int crow = (lane >> 4) * 4, ccol = lane & 15;
  if constexpr (MODE == 2) {
    // scatter: row=(b,t), col=(g,n,d) -> Wx_rec[((b*8+n)*1024+t)*512 + d*4 + g]
    bf16* C = (bf16*)Cout;
#pragma unroll
    for (int i = 0; i < 4; ++i)
#pragma unroll
      for (int j = 0; j < 4; ++j) {
        const int col = n0 + wn * 64 + j * 16 + ccol;
        const int g = col >> 10, nn = (col >> 7) & 7, dd = col & 127;
#pragma unroll
        for (int jj = 0; jj < 4; ++jj) {
          const int row = m0 + wm * 64 + i * 16 + crow + jj;
          const int b = row >> 10, t = row & 1023;
          C[(((size_t)(b * 8 + nn) * 1024 + t) << 9) + dd * 4 + g] =
              __float2bfloat16(acc[i][j][jj]);
        }
      }
  } else {
    float* C = (float*)Cout;
    float bv[4];
#pragma unroll
    for (int j = 0; j < 4; ++j) bv[j] = bp[n0 + wn * 64 + j * 16 + ccol];
#pragma unroll
    for (int i = 0; i < 4; ++i)
#pragma unroll
      for (int j = 0; j < 4; ++j) {
        const size_t base =
            (size_t)(m0 + wm * 64 + i * 16 + crow) * N + (n0 + wn * 64 + j * 16 + ccol);
#pragma unroll
        for (int jj = 0; jj < 4; ++jj)
          C[base + (size_t)jj * N] = acc[i][j][jj] + bv[j];
      }
  }
}

// ---------------------------------------------------------------------------
// LSTM recurrence via MFMA broadcast. v8: TWO chains per WG on SEPARATE
// half-wave-groups (16 waves, 1024 threads). Waves 0-7 advance chain 2*wg,
// waves 8-15 advance chain 2*wg+1. 4 waves/SIMD: while one chain's waves sit
// in their serial dependency chain, the other chain's waves issue -> the
// ~60% per-SIMD idle measured in r7 gets filled. Inner loop = r7's.
// ---------------------------------------------------------------------------
__global__ __launch_bounds__(1024, 4) void lstm_mfma(const bf16* __restrict__ Wx,
                                                     const float* __restrict__ R,
                                                     const float* __restrict__ bias,
                                                     bf16* __restrict__ h_all) {
  const int wg = blockIdx.x;
  const int tid = threadIdx.x;
  const int w = tid >> 6, lane = tid & 63;
  const int ch = w >> 3;           // chain slot within WG (0,1)
  const int wv = w & 7;            // wave within chain group
  const int cid = wg * 2 + ch;     // global chain id = b*8+n
  const int bb = cid >> 3;         // batch
  const int n = cid & 7;           // head
  const int lg = lane >> 4;        // k-slice group 0..3
  const int lc = lane & 15;        // col within fragment
  const int d = wv * 16 + lc;      // this lane's d

  // B fragments: lane holds R[g, n, d, 32*kf + 8*lg + j], j=0..7 (bf16)
  short8v Bf[4][4];
#pragma unroll
  for (int g = 0; g < 4; ++g)
#pragma unroll
    for (int kf = 0; kf < 4; ++kf) {
      const float* rp = R + (size_t)((g * Nq + n) * Dq + d) * Dq + 32 * kf + 8 * lg;
      const float4 r0 = *(const float4*)rp;
      const float4 r1 = *(const float4*)(rp + 4);
      short8v bv;
      bv[0] = (short)bfu(r0.x); bv[1] = (short)bfu(r0.y);
      bv[2] = (short)bfu(r0.z); bv[3] = (short)bfu(r0.w);
      bv[4] = (short)bfu(r1.x); bv[5] = (short)bfu(r1.y);
      bv[6] = (short)bfu(r1.z); bv[7] = (short)bfu(r1.w);
      Bf[g][kf] = bv;
    }

  float bvf[4];
#pragma unroll
  for (int g = 0; g < 4; ++g) bvf[g] = bias[(g * Nq + n) * Dq + d];

  __shared__ __align__(16) bf16 hbuf[2][2][128];  // [chain][dbuf][d]
  if (tid < 256) hbuf[tid >> 7][0][tid & 127] = __float2bfloat16(0.f);
  __syncthreads();

  // Wx_rec layout: [cid*1024 + t][d*4 + g], row size 512 bf16
  const bf16* wx0 = Wx + ((size_t)cid << 19) + d * 4;
  bf16* hallp = h_all + ((size_t)(bb * Tq) * Nq + n) * Dq + d;

  // 4-deep static prefetch pipeline: one 8B load per step
  ushort4 wxr[4];
#pragma unroll
  for (int u = 0; u < 4; ++u)
    wxr[u] = *(const ushort4*)(wx0 + ((size_t)u << 9));

  float c = 0.f;
  // persistent accumulators: elements 1-3 are don't-care (never read)
  f32x4 accA[4] = {}, accB[4] = {};

  for (int t0 = 0; t0 < Tq; t0 += 4) {
#pragma unroll
    for (int u = 0; u < 4; ++u) {
      const int t = t0 + u;
      // A fragments: every lane reads h[32*kf + 8*lg .. +8] (broadcast groups)
      const bf16* hb = hbuf[ch][t & 1];
      short8v Af0 = *(const short8v*)(hb + 8 * lg);
      short8v Af1 = *(const short8v*)(hb + 32 + 8 * lg);
      short8v Af2 = *(const short8v*)(hb + 64 + 8 * lg);
      short8v Af3 = *(const short8v*)(hb + 96 + 8 * lg);

      // decode this step's wx (4 gates) and set ONLY element 0 of the accs
#pragma unroll
      for (int g = 0; g < 4; ++g) {
        const unsigned ub = (g == 0) ? wxr[u].x : (g == 1) ? wxr[u].y
                          : (g == 2) ? wxr[u].z : wxr[u].w;
        accA[g][0] = __uint_as_float(ub << 16) + bvf[g];
        accB[g][0] = 0.f;
      }

      // depth-2 MFMA chains: accA gets kf 0,1; accB gets kf 2,3
#pragma unroll
      for (int g = 0; g < 4; ++g) {
        accA[g] = __builtin_amdgcn_mfma_f32_16x16x32_bf16(Af0, Bf[g][0], accA[g], 0, 0, 0);
        accB[g] = __builtin_amdgcn_mfma_f32_16x16x32_bf16(Af2, Bf[g][2], accB[g], 0, 0, 0);
      }
#pragma unroll
      for (int g = 0; g < 4; ++g) {
        accA[g] = __builtin_amdgcn_mfma_f32_16x16x32_bf16(Af1, Bf[g][1], accA[g], 0, 0, 0);
        accB[g] = __builtin_amdgcn_mfma_f32_16x16x32_bf16(Af3, Bf[g][3], accB[g], 0, 0, 0);
      }

      // prefetch wx for step t+4 into the SAME static slot
      {
        const int tp = (t + 4 < Tq) ? (t + 4) : (Tq - 1);
        wxr[u] = *(const ushort4*)(wx0 + ((size_t)tp << 9));
      }

      const float i_ = sigm(accA[0][0] + accB[0][0]);
      const float f_ = sigm(accA[1][0] + accB[1][0]);
      const float z_ = tanh_(accA[2][0] + accB[2][0]);
      const float o_ = sigm(accA[3][0] + accB[3][0]);
      c = f_ * c + i_ * z_;
      const float h = o_ * tanh_(c);
      const bf16 h16 = __float2bfloat16(h);

      if (lg == 0) {
        hbuf[ch][(t + 1) & 1][d] = h16;
        hallp[(size_t)t * (Nq * Dq)] = h16;
      }
      // barrier WITHOUT vmcnt drain: only LDS visibility needed.
      __builtin_amdgcn_sched_barrier(0);
      asm volatile("s_waitcnt lgkmcnt(0)" ::: "memory");
      __builtin_amdgcn_sched_barrier(0);
      __builtin_amdgcn_s_barrier();
      __builtin_amdgcn_sched_barrier(0);
    }
  }
}

// ---------------------------------------------------------------------------
extern "C" void kernel_launch(void* const* d_in, const int* in_sizes, int n_in,
                              void* d_out, int out_size, void* d_ws, size_t ws_size,
                              hipStream_t stream) {
  const float* x_emb = (const float*)d_in[0];  // [16,1024,1024]
  const float* W_in  = (const float*)d_in[1];  // [1024,4096]
  const float* R     = (const float*)d_in[2];  // [4,8,128,128]
  const float* bias  = (const float*)d_in[3];  // [4,8,128]
  const float* W_prj = (const float*)d_in[4];  // [2048,1024]
  const float* b_prj = (const float*)d_in[5];  // [2048]

  char* ws = (char*)d_ws;
  bf16* xb  = (bf16*)ws;                               // 32 MB
  bf16* WiT = (bf16*)(ws + (size_t)M1 * K1 * 2);       //  8 MB
  bf16* Wpb = WiT + (size_t)N1q * K1;                  //  4 MB
  bf16* H   = Wpb + (size_t)N2 * K2;                   // 32 MB
  bf16* Wx = (bf16*)d_out;                             // 134 MB, dead before gemm_out

  cast_f32_bf16<<<(M1 * K1 / 4 + 255) / 256, 256, 0, stream>>>(x_emb, xb, M1 * K1 / 4);
  transpose_cast<<<dim3(N1q / 32, K1 / 32), 256, 0, stream>>>(W_in, WiT, K1, N1q);
  cast_f32_bf16<<<(N2 * K2 / 4 + 255) / 256, 256, 0, stream>>>(W_prj, Wpb, N2 * K2 / 4);

  gemm_bt<2><<<dim3(N1q / 128, M1 / 128), 256, 0, stream>>>(
      xb, WiT, (void*)Wx, nullptr, K1, N1q);

  lstm_mfma<<<dim3(64), 1024, 0, stream>>>(Wx, R, bias, H);

  gemm_bt<0><<<dim3(N2 / 128, M1 / 128), 256, 0, stream>>>(
      H, Wpb, d_out, b_prj, K2, N2);
}

// Round 9
// 1927.384 us; speedup vs baseline: 1.0005x; 1.0005x over previous
//
#include <hip/hip_runtime.h>
#include <hip/hip_bf16.h>

#define DEV __device__ __forceinline__

using bf16 = __hip_bfloat16;
typedef __attribute__((ext_vector_type(8))) short short8v;  // 8 bf16 = 4 VGPRs
typedef __attribute__((ext_vector_type(4))) float f32x4;

constexpr int Bq = 16, Tq = 1024, Eq = 1024, Gq = 4, Nq = 8, Dq = 128, Vq = 2048;
constexpr int M1 = Bq * Tq;        // 16384
constexpr int N1q = Gq * Nq * Dq;  // 4096
constexpr int K1 = Eq;             // 1024
constexpr int K2 = Nq * Dq;        // 1024
constexpr int N2 = Vq;             // 2048

DEV unsigned short bfu(float x) {
  union { bf16 h; unsigned short u; } cv;
  cv.h = __float2bfloat16(x);
  return cv.u;
}

DEV float rcp_(float x) { return __builtin_amdgcn_rcpf(x); }
DEV float sigm(float x) { return rcp_(1.0f + __expf(-x)); }
DEV float tanh_(float x) { return fmaf(2.0f, rcp_(1.0f + __expf(-2.0f * x)), -1.0f); }

// async global->LDS, 16B per lane; LDS dest is wave-uniform base + lane*16
#define GLD16(gp, lp)                                                       \
  __builtin_amdgcn_global_load_lds(                                        \
      (const __attribute__((address_space(1))) void*)(gp),                 \
      (__attribute__((address_space(3))) void*)(lp), 16, 0, 0)

// ---------------------------------------------------------------------------
// Prep kernels: casts + transpose-cast
// ---------------------------------------------------------------------------
__global__ __launch_bounds__(256) void cast_f32_bf16(const float* __restrict__ s,
                                                     bf16* __restrict__ d, int n4) {
  const int i = blockIdx.x * 256 + threadIdx.x;
  if (i >= n4) return;
  const float4 v = ((const float4*)s)[i];
  ushort4 u;
  u.x = bfu(v.x); u.y = bfu(v.y); u.z = bfu(v.z); u.w = bfu(v.w);
  ((ushort4*)d)[i] = u;
}

// s: [SK][SN] f32 row-major  ->  d: [SN][SK] bf16 row-major
__global__ __launch_bounds__(256) void transpose_cast(const float* __restrict__ s,
                                                      bf16* __restrict__ d,
                                                      int SK, int SN) {
  __shared__ float t[32][33];
  const int n0 = blockIdx.x * 32, k0 = blockIdx.y * 32;
  const int tx = threadIdx.x & 31, ty = threadIdx.x >> 5;  // ty: 0..7
#pragma unroll
  for (int i = 0; i < 32; i += 8)
    t[ty + i][tx] = s[(size_t)(k0 + ty + i) * SN + n0 + tx];
  __syncthreads();
#pragma unroll
  for (int i = 0; i < 32; i += 8)
    d[(size_t)(n0 + ty + i) * SK + k0 + tx] = __float2bfloat16(t[tx][ty + i]);
}

// ---------------------------------------------------------------------------
// bf16 MFMA GEMM, m97 structure: C[M,N] = A[M,K] @ Bt[N,K]^T
// MODE 0: f32 out + bias.  MODE 2: bf16 out scattered to Wx_rec[b,n,t,d,g].
// ---------------------------------------------------------------------------
template <int MODE>
__global__ __launch_bounds__(256) void gemm_bt(const bf16* __restrict__ A,
                                               const bf16* __restrict__ Bt,
                                               void* __restrict__ Cout,
                                               const float* __restrict__ bp,
                                               int K, int N) {
  __shared__ bf16 As[128 * 32];
  __shared__ bf16 Bs[128 * 32];
  const int m0 = blockIdx.y * 128, n0 = blockIdx.x * 128;
  const int tid = threadIdx.x;
  const int lane = tid & 63, w = tid >> 6;
  const int wm = w >> 1, wn = w & 1;

  const int srow = lane >> 2, scol = (lane & 3) * 8;
  const int ca = w * 2;
  const bf16* Ag0 = A + (size_t)(m0 + ca * 16 + srow) * K + scol;
  const bf16* Ag1 = Ag0 + (size_t)16 * K;
  const bf16* Bg0 = Bt + (size_t)(n0 + ca * 16 + srow) * K + scol;
  const bf16* Bg1 = Bg0 + (size_t)16 * K;
  bf16* Al0 = As + ca * 512;
  bf16* Al1 = Al0 + 512;
  bf16* Bl0 = Bs + ca * 512;
  bf16* Bl1 = Bl0 + 512;

  f32x4 acc[4][4] = {};

  const int rr = lane & 15;
  const int kb = (lane >> 4) * 8;

  for (int k0 = 0; k0 < K; k0 += 32) {
    GLD16(Ag0 + k0, Al0);
    GLD16(Ag1 + k0, Al1);
    GLD16(Bg0 + k0, Bl0);
    GLD16(Bg1 + k0, Bl1);
    __syncthreads();
    short8v af[4], bfr[4];
#pragma unroll
    for (int i = 0; i < 4; ++i) {
      af[i]  = *(const short8v*)&As[(wm * 64 + i * 16 + rr) * 32 + kb];
      bfr[i] = *(const short8v*)&Bs[(wn * 64 + i * 16 + rr) * 32 + kb];
    }
#pragma unroll
    for (int i = 0; i < 4; ++i)
#pragma unroll
      for (int j = 0; j < 4; ++j)
        acc[i][j] = __builtin_amdgcn_mfma_f32_16x16x32_bf16(af[i], bfr[j], acc[i][j], 0, 0, 0);
    __syncthreads();
  }

  const int crow = (lane >> 4) * 4, ccol = lane & 15;
  if constexpr (MODE == 2) {
    // scatter: row=(b,t), col=(g,n,d) -> Wx_rec[((b*8+n)*1024+t)*512 + d*4 + g]
    bf16* C = (bf16*)Cout;
#pragma unroll
    for (int i = 0; i < 4; ++i)
#pragma unroll
      for (int j = 0; j < 4; ++j) {
        const int col = n0 + wn * 64 + j * 16 + ccol;
        const int g = col >> 10, nn = (col >> 7) & 7, dd = col & 127;
#pragma unroll
        for (int jj = 0; jj < 4; ++jj) {
          const int row = m0 + wm * 64 + i * 16 + crow + jj;
          const int b = row >> 10, t = row & 1023;
          C[(((size_t)(b * 8 + nn) * 1024 + t) << 9) + dd * 4 + g] =
              __float2bfloat16(acc[i][j][jj]);
        }
      }
  } else {
    float* C = (float*)Cout;
    float bv[4];
#pragma unroll
    for (int j = 0; j < 4; ++j) bv[j] = bp[n0 + wn * 64 + j * 16 + ccol];
#pragma unroll
    for (int i = 0; i < 4; ++i)
#pragma unroll
      for (int j = 0; j < 4; ++j) {
        const size_t base =
            (size_t)(m0 + wm * 64 + i * 16 + crow) * N + (n0 + wn * 64 + j * 16 + ccol);
#pragma unroll
        for (int jj = 0; jj < 4; ++jj)
          C[base + (size_t)jj * N] = acc[i][j][jj] + bv[j];
      }
  }
}

// ---------------------------------------------------------------------------
// LSTM recurrence via MFMA broadcast. v9 = v8 structure (two chains per WG on
// separate 8-wave groups, 16 waves, 4 waves/SIMD) with the SPILL FIXED:
// plain __launch_bounds__(1024) -> VGPR cap 128, Bf stays in registers.
// Between barriers each SIMD has 4 independent instruction streams
// (2 waves x 2 chains at independent data) -> fills r7's 62% idle.
// ---------------------------------------------------------------------------
__global__ __launch_bounds__(1024) void lstm_mfma(const bf16* __restrict__ Wx,
                                                  const float* __restrict__ R,
                                                  const float* __restrict__ bias,
                                                  bf16* __restrict__ h_all) {
  const int wg = blockIdx.x;
  const int tid = threadIdx.x;
  const int w = tid >> 6, lane = tid & 63;
  const int ch = w >> 3;           // chain slot within WG (0,1)
  const int wv = w & 7;            // wave within chain group
  const int cid = wg * 2 + ch;     // global chain id = b*8+n
  const int bb = cid >> 3;         // batch
  const int n = cid & 7;           // head
  const int lg = lane >> 4;        // k-slice group 0..3
  const int lc = lane & 15;        // col within fragment
  const int d = wv * 16 + lc;      // this lane's d

  // B fragments: lane holds R[g, n, d, 32*kf + 8*lg + j], j=0..7 (bf16)
  short8v Bf[4][4];
#pragma unroll
  for (int g = 0; g < 4; ++g)
#pragma unroll
    for (int kf = 0; kf < 4; ++kf) {
      const float* rp = R + (size_t)((g * Nq + n) * Dq + d) * Dq + 32 * kf + 8 * lg;
      const float4 r0 = *(const float4*)rp;
      const float4 r1 = *(const float4*)(rp + 4);
      short8v bv;
      bv[0] = (short)bfu(r0.x); bv[1] = (short)bfu(r0.y);
      bv[2] = (short)bfu(r0.z); bv[3] = (short)bfu(r0.w);
      bv[4] = (short)bfu(r1.x); bv[5] = (short)bfu(r1.y);
      bv[6] = (short)bfu(r1.z); bv[7] = (short)bfu(r1.w);
      Bf[g][kf] = bv;
    }

  float bvf[4];
#pragma unroll
  for (int g = 0; g < 4; ++g) bvf[g] = bias[(g * Nq + n) * Dq + d];

  __shared__ __align__(16) bf16 hbuf[2][2][128];  // [chain][dbuf][d]
  if (tid < 256) hbuf[tid >> 7][0][tid & 127] = __float2bfloat16(0.f);
  __syncthreads();

  // Wx_rec layout: [cid*1024 + t][d*4 + g], row size 512 bf16
  const bf16* wx0 = Wx + ((size_t)cid << 19) + d * 4;
  bf16* hallp = h_all + ((size_t)(bb * Tq) * Nq + n) * Dq + d;

  // 4-deep static prefetch pipeline: one 8B load per step
  ushort4 wxr[4];
#pragma unroll
  for (int u = 0; u < 4; ++u)
    wxr[u] = *(const ushort4*)(wx0 + ((size_t)u << 9));

  float c = 0.f;
  // persistent accumulators: elements 1-3 are don't-care (never read)
  f32x4 accA[4] = {}, accB[4] = {};

  for (int t0 = 0; t0 < Tq; t0 += 4) {
#pragma unroll
    for (int u = 0; u < 4; ++u) {
      const int t = t0 + u;
      // A fragments: every lane reads h[32*kf + 8*lg .. +8] (broadcast groups)
      const bf16* hb = hbuf[ch][t & 1];
      short8v Af0 = *(const short8v*)(hb + 8 * lg);
      short8v Af1 = *(const short8v*)(hb + 32 + 8 * lg);
      short8v Af2 = *(const short8v*)(hb + 64 + 8 * lg);
      short8v Af3 = *(const short8v*)(hb + 96 + 8 * lg);

      // decode this step's wx (4 gates) and set ONLY element 0 of the accs
#pragma unroll
      for (int g = 0; g < 4; ++g) {
        const unsigned ub = (g == 0) ? wxr[u].x : (g == 1) ? wxr[u].y
                          : (g == 2) ? wxr[u].z : wxr[u].w;
        accA[g][0] = __uint_as_float(ub << 16) + bvf[g];
        accB[g][0] = 0.f;
      }

      // depth-2 MFMA chains: accA gets kf 0,1; accB gets kf 2,3
#pragma unroll
      for (int g = 0; g < 4; ++g) {
        accA[g] = __builtin_amdgcn_mfma_f32_16x16x32_bf16(Af0, Bf[g][0], accA[g], 0, 0, 0);
        accB[g] = __builtin_amdgcn_mfma_f32_16x16x32_bf16(Af2, Bf[g][2], accB[g], 0, 0, 0);
      }
#pragma unroll
      for (int g = 0; g < 4; ++g) {
        accA[g] = __builtin_amdgcn_mfma_f32_16x16x32_bf16(Af1, Bf[g][1], accA[g], 0, 0, 0);
        accB[g] = __builtin_amdgcn_mfma_f32_16x16x32_bf16(Af3, Bf[g][3], accB[g], 0, 0, 0);
      }

      // prefetch wx for step t+4 into the SAME static slot
      {
        const int tp = (t + 4 < Tq) ? (t + 4) : (Tq - 1);
        wxr[u] = *(const ushort4*)(wx0 + ((size_t)tp << 9));
      }

      const float i_ = sigm(accA[0][0] + accB[0][0]);
      const float f_ = sigm(accA[1][0] + accB[1][0]);
      const float z_ = tanh_(accA[2][0] + accB[2][0]);
      const float o_ = sigm(accA[3][0] + accB[3][0]);
      c = f_ * c + i_ * z_;
      const float h = o_ * tanh_(c);
      const bf16 h16 = __float2bfloat16(h);

      if (lg == 0) {
        hbuf[ch][(t + 1) & 1][d] = h16;
        hallp[(size_t)t * (Nq * Dq)] = h16;
      }
      // barrier WITHOUT vmcnt drain: only LDS visibility needed.
      __builtin_amdgcn_sched_barrier(0);
      asm volatile("s_waitcnt lgkmcnt(0)" ::: "memory");
      __builtin_amdgcn_sched_barrier(0);
      __builtin_amdgcn_s_barrier();
      __builtin_amdgcn_sched_barrier(0);
    }
  }
}

// ---------------------------------------------------------------------------
extern "C" void kernel_launch(void* const* d_in, const int* in_sizes, int n_in,
                              void* d_out, int out_size, void* d_ws, size_t ws_size,
                              hipStream_t stream) {
  const float* x_emb = (const float*)d_in[0];  // [16,1024,1024]
  const float* W_in  = (const float*)d_in[1];  // [1024,4096]
  const float* R     = (const float*)d_in[2];  // [4,8,128,128]
  const float* bias  = (const float*)d_in[3];  // [4,8,128]
  const float* W_prj = (const float*)d_in[4];  // [2048,1024]
  const float* b_prj = (const float*)d_in[5];  // [2048]

  char* ws = (char*)d_ws;
  bf16* xb  = (bf16*)ws;                               // 32 MB
  bf16* WiT = (bf16*)(ws + (size_t)M1 * K1 * 2);       //  8 MB
  bf16* Wpb = WiT + (size_t)N1q * K1;                  //  4 MB
  bf16* H   = Wpb + (size_t)N2 * K2;                   // 32 MB
  bf16* Wx = (bf16*)d_out;                             // 134 MB, dead before gemm_out

  cast_f32_bf16<<<(M1 * K1 / 4 + 255) / 256, 256, 0, stream>>>(x_emb, xb, M1 * K1 / 4);
  transpose_cast<<<dim3(N1q / 32, K1 / 32), 256, 0, stream>>>(W_in, WiT, K1, N1q);
  cast_f32_bf16<<<(N2 * K2 / 4 + 255) / 256, 256, 0, stream>>>(W_prj, Wpb, N2 * K2 / 4);

  gemm_bt<2><<<dim3(N1q / 128, M1 / 128), 256, 0, stream>>>(
      xb, WiT, (void*)Wx, nullptr, K1, N1q);

  lstm_mfma<<<dim3(64), 1024, 0, stream>>>(Wx, R, bias, H);

  gemm_bt<0><<<dim3(N2 / 128, M1 / 128), 256, 0, stream>>>(
      H, Wpb, d_out, b_prj, K2, N2);
}

// Round 10
// 1497.071 us; speedup vs baseline: 1.2881x; 1.2874x over previous
//
#include <hip/hip_runtime.h>
#include <hip/hip_bf16.h>

#define DEV __device__ __forceinline__

using bf16 = __hip_bfloat16;
typedef __attribute__((ext_vector_type(8))) short short8v;  // 8 bf16 = 4 VGPRs
typedef __attribute__((ext_vector_type(4))) float f32x4;

constexpr int Bq = 16, Tq = 1024, Eq = 1024, Gq = 4, Nq = 8, Dq = 128, Vq = 2048;
constexpr int M1 = Bq * Tq;        // 16384
constexpr int N1q = Gq * Nq * Dq;  // 4096
constexpr int K1 = Eq;             // 1024
constexpr int K2 = Nq * Dq;        // 1024
constexpr int N2 = Vq;             // 2048

DEV unsigned short bfu(float x) {
  union { bf16 h; unsigned short u; } cv;
  cv.h = __float2bfloat16(x);
  return cv.u;
}

DEV float rcp_(float x) { return __builtin_amdgcn_rcpf(x); }
DEV float sigm(float x) { return rcp_(1.0f + __expf(-x)); }
DEV float tanh_(float x) { return fmaf(2.0f, rcp_(1.0f + __expf(-2.0f * x)), -1.0f); }

// async global->LDS, 16B per lane; LDS dest is wave-uniform base + lane*16
#define GLD16(gp, lp)                                                       \
  __builtin_amdgcn_global_load_lds(                                        \
      (const __attribute__((address_space(1))) void*)(gp),                 \
      (__attribute__((address_space(3))) void*)(lp), 16, 0, 0)

// ---------------------------------------------------------------------------
// Prep kernels: casts + transpose-cast
// ---------------------------------------------------------------------------
__global__ __launch_bounds__(256) void cast_f32_bf16(const float* __restrict__ s,
                                                     bf16* __restrict__ d, int n4) {
  const int i = blockIdx.x * 256 + threadIdx.x;
  if (i >= n4) return;
  const float4 v = ((const float4*)s)[i];
  ushort4 u;
  u.x = bfu(v.x); u.y = bfu(v.y); u.z = bfu(v.z); u.w = bfu(v.w);
  ((ushort4*)d)[i] = u;
}

// s: [SK][SN] f32 row-major  ->  d: [SN][SK] bf16 row-major
__global__ __launch_bounds__(256) void transpose_cast(const float* __restrict__ s,
                                                      bf16* __restrict__ d,
                                                      int SK, int SN) {
  __shared__ float t[32][33];
  const int n0 = blockIdx.x * 32, k0 = blockIdx.y * 32;
  const int tx = threadIdx.x & 31, ty = threadIdx.x >> 5;  // ty: 0..7
#pragma unroll
  for (int i = 0; i < 32; i += 8)
    t[ty + i][tx] = s[(size_t)(k0 + ty + i) * SN + n0 + tx];
  __syncthreads();
#pragma unroll
  for (int i = 0; i < 32; i += 8)
    d[(size_t)(n0 + ty + i) * SK + k0 + tx] = __float2bfloat16(t[tx][ty + i]);
}

// ---------------------------------------------------------------------------
// bf16 MFMA GEMM, m97 structure: C[M,N] = A[M,K] @ Bt[N,K]^T
// MODE 0: f32 out + bias.
// MODE 2: bf16 out + bias folded, scattered to Wx_rec[n][t][g][d][b].
// ---------------------------------------------------------------------------
template <int MODE>
__global__ __launch_bounds__(256) void gemm_bt(const bf16* __restrict__ A,
                                               const bf16* __restrict__ Bt,
                                               void* __restrict__ Cout,
                                               const float* __restrict__ bp,
                                               int K, int N) {
  __shared__ bf16 As[128 * 32];
  __shared__ bf16 Bs[128 * 32];
  const int m0 = blockIdx.y * 128, n0 = blockIdx.x * 128;
  const int tid = threadIdx.x;
  const int lane = tid & 63, w = tid >> 6;
  const int wm = w >> 1, wn = w & 1;

  const int srow = lane >> 2, scol = (lane & 3) * 8;
  const int ca = w * 2;
  const bf16* Ag0 = A + (size_t)(m0 + ca * 16 + srow) * K + scol;
  const bf16* Ag1 = Ag0 + (size_t)16 * K;
  const bf16* Bg0 = Bt + (size_t)(n0 + ca * 16 + srow) * K + scol;
  const bf16* Bg1 = Bg0 + (size_t)16 * K;
  bf16* Al0 = As + ca * 512;
  bf16* Al1 = Al0 + 512;
  bf16* Bl0 = Bs + ca * 512;
  bf16* Bl1 = Bl0 + 512;

  f32x4 acc[4][4] = {};

  const int rr = lane & 15;
  const int kb = (lane >> 4) * 8;

  for (int k0 = 0; k0 < K; k0 += 32) {
    GLD16(Ag0 + k0, Al0);
    GLD16(Ag1 + k0, Al1);
    GLD16(Bg0 + k0, Bl0);
    GLD16(Bg1 + k0, Bl1);
    __syncthreads();
    short8v af[4], bfr[4];
#pragma unroll
    for (int i = 0; i < 4; ++i) {
      af[i]  = *(const short8v*)&As[(wm * 64 + i * 16 + rr) * 32 + kb];
      bfr[i] = *(const short8v*)&Bs[(wn * 64 + i * 16 + rr) * 32 + kb];
    }
#pragma unroll
    for (int i = 0; i < 4; ++i)
#pragma unroll
      for (int j = 0; j < 4; ++j)
        acc[i][j] = __builtin_amdgcn_mfma_f32_16x16x32_bf16(af[i], bfr[j], acc[i][j], 0, 0, 0);
    __syncthreads();
  }

  const int crow = (lane >> 4) * 4, ccol = lane & 15;
  if constexpr (MODE == 2) {
    // col=(g,n,d); row=(b,t). bias folded here (f32 add before bf16 round).
    // Wx_rec[((n*1024+t)*4+g)*128+d][b] : addr = (((n*1024+t)*4+g)*128+d)*16+b
    bf16* C = (bf16*)Cout;
#pragma unroll
    for (int i = 0; i < 4; ++i)
#pragma unroll
      for (int j = 0; j < 4; ++j) {
        const int col = n0 + wn * 64 + j * 16 + ccol;
        const int g = col >> 10, nn = (col >> 7) & 7, dd = col & 127;
        const float bvj = bp[(g * 8 + nn) * 128 + dd];
#pragma unroll
        for (int jj = 0; jj < 4; ++jj) {
          const int row = m0 + wm * 64 + i * 16 + crow + jj;
          const int b = row >> 10, t = row & 1023;
          const size_t idx =
              ((((size_t)nn * 1024 + t) * 4 + g) * 128 + dd) * 16 + b;
          C[idx] = __float2bfloat16(acc[i][j][jj] + bvj);
        }
      }
  } else {
    float* C = (float*)Cout;
    float bv[4];
#pragma unroll
    for (int j = 0; j < 4; ++j) bv[j] = bp[n0 + wn * 64 + j * 16 + ccol];
#pragma unroll
    for (int i = 0; i < 4; ++i)
#pragma unroll
      for (int j = 0; j < 4; ++j) {
        const size_t base =
            (size_t)(m0 + wm * 64 + i * 16 + crow) * N + (n0 + wn * 64 + j * 16 + ccol);
#pragma unroll
        for (int jj = 0; jj < 4; ++jj)
          C[base + (size_t)jj * N] = acc[i][j][jj] + bv[j];
      }
  }
}

// ---------------------------------------------------------------------------
// LSTM recurrence, v10: BATCHED MFMA. One WG per head n (8 WGs, 512 thr).
// Per step: gates[16b x 512(d,g)] = h[16b x 128e] @ R_n^T — A-rows are REAL
// batches (no broadcast waste). Wave w owns d in [16w,16w+16), all 4 gates.
// acc C-layout: lane(lg,lc) jj -> gates[b=lg*4+jj][d=16w+lc]; each lane does
// 4 full c-updates. 16 chains advance per WG-step (16x r7's work/step).
// h exchanged via double-buffered LDS [2][16][136] (272B pitch, ~2-way).
// wx pre-scattered [n][t][g][d][b] + bias folded -> 4x 8B loads/step.
// ---------------------------------------------------------------------------
__global__ __launch_bounds__(512, 2) void lstm_mfma(const bf16* __restrict__ Wx,
                                                    const float* __restrict__ R,
                                                    bf16* __restrict__ h_all) {
  const int n = blockIdx.x;        // head
  const int tid = threadIdx.x;
  const int w = tid >> 6, lane = tid & 63;
  const int lg = lane >> 4;        // 0..3
  const int lc = lane & 15;
  const int d = w * 16 + lc;       // this lane's d (col)

  // B fragments (same as r7): lane holds R[g, n, d, 32*kf + 8*lg + j]
  short8v Bf[4][4];
#pragma unroll
  for (int g = 0; g < 4; ++g)
#pragma unroll
    for (int kf = 0; kf < 4; ++kf) {
      const float* rp = R + (size_t)((g * Nq + n) * Dq + d) * Dq + 32 * kf + 8 * lg;
      const float4 r0 = *(const float4*)rp;
      const float4 r1 = *(const float4*)(rp + 4);
      short8v bv;
      bv[0] = (short)bfu(r0.x); bv[1] = (short)bfu(r0.y);
      bv[2] = (short)bfu(r0.z); bv[3] = (short)bfu(r0.w);
      bv[4] = (short)bfu(r1.x); bv[5] = (short)bfu(r1.y);
      bv[6] = (short)bfu(r1.z); bv[7] = (short)bfu(r1.w);
      Bf[g][kf] = bv;
    }

  // h LDS: [dbuf][b][e] ushort, pitch 136 (272B) to spread banks
  __shared__ __align__(16) unsigned short hl[2][16][136];
  for (int i = tid; i < 16 * 136; i += 512) (&hl[0][0][0])[i] = 0;  // bf16 0.0
  __syncthreads();

  // wx base: [n][t][g][d][b], addr = (n<<23) + (t<<13) + (g<<11) + d*16 + lg*4
  const bf16* wxb = Wx + ((size_t)n << 23) + d * 16 + lg * 4;
  // h_all: [(b*1024+t)*1024 + n*128 + d]
  bf16* hout = h_all + n * 128 + d;

  // 4-deep static prefetch: 4 gates x ushort4 (b = lg*4..+4) per step
  ushort4 wxr[4][4];
#pragma unroll
  for (int u = 0; u < 4; ++u)
#pragma unroll
    for (int g = 0; g < 4; ++g)
      wxr[u][g] = *(const ushort4*)(wxb + ((size_t)u << 13) + (g << 11));

  float cst[4] = {0.f, 0.f, 0.f, 0.f};  // c for b = lg*4 + jj

  for (int t0 = 0; t0 < Tq; t0 += 4) {
#pragma unroll
    for (int u = 0; u < 4; ++u) {
      const int t = t0 + u;
      // A fragments: row b = lc, k = kf*32 + lg*8 + j
      const unsigned short* hb = &hl[t & 1][0][0];
      short8v Af[4];
#pragma unroll
      for (int kf = 0; kf < 4; ++kf)
        Af[kf] = *(const short8v*)(hb + lc * 136 + kf * 32 + lg * 8);

      // acc init = wx (+bias already folded), all 4 rows per lane
      f32x4 acc[4];
#pragma unroll
      for (int g = 0; g < 4; ++g) {
        acc[g][0] = __uint_as_float((unsigned)wxr[u][g].x << 16);
        acc[g][1] = __uint_as_float((unsigned)wxr[u][g].y << 16);
        acc[g][2] = __uint_as_float((unsigned)wxr[u][g].z << 16);
        acc[g][3] = __uint_as_float((unsigned)wxr[u][g].w << 16);
      }
#pragma unroll
      for (int kf = 0; kf < 4; ++kf)
#pragma unroll
        for (int g = 0; g < 4; ++g)
          acc[g] = __builtin_amdgcn_mfma_f32_16x16x32_bf16(Af[kf], Bf[g][kf], acc[g], 0, 0, 0);

      // prefetch wx for step t+4 into the SAME static slot
      {
        const int tp = (t + 4 < Tq) ? (t + 4) : (Tq - 1);
#pragma unroll
        for (int g = 0; g < 4; ++g)
          wxr[u][g] = *(const ushort4*)(wxb + ((size_t)tp << 13) + (g << 11));
      }

      // 4 real c-updates per lane (b = lg*4 + jj)
#pragma unroll
      for (int jj = 0; jj < 4; ++jj) {
        const float i_ = sigm(acc[0][jj]);
        const float f_ = sigm(acc[1][jj]);
        const float z_ = tanh_(acc[2][jj]);
        const float o_ = sigm(acc[3][jj]);
        cst[jj] = f_ * cst[jj] + i_ * z_;
        const float h = o_ * tanh_(cst[jj]);
        const bf16 h16 = __float2bfloat16(h);
        const int b = lg * 4 + jj;
        hl[(t + 1) & 1][b][d] = ((unsigned short*)&h16)[0];
        hout[((size_t)b << 20) + ((size_t)t << 10)] = h16;
      }

      // barrier WITHOUT vmcnt drain: only LDS visibility needed.
      __builtin_amdgcn_sched_barrier(0);
      asm volatile("s_waitcnt lgkmcnt(0)" ::: "memory");
      __builtin_amdgcn_sched_barrier(0);
      __builtin_amdgcn_s_barrier();
      __builtin_amdgcn_sched_barrier(0);
    }
  }
}

// ---------------------------------------------------------------------------
extern "C" void kernel_launch(void* const* d_in, const int* in_sizes, int n_in,
                              void* d_out, int out_size, void* d_ws, size_t ws_size,
                              hipStream_t stream) {
  const float* x_emb = (const float*)d_in[0];  // [16,1024,1024]
  const float* W_in  = (const float*)d_in[1];  // [1024,4096]
  const float* R     = (const float*)d_in[2];  // [4,8,128,128]
  const float* bias  = (const float*)d_in[3];  // [4,8,128]
  const float* W_prj = (const float*)d_in[4];  // [2048,1024]
  const float* b_prj = (const float*)d_in[5];  // [2048]

  char* ws = (char*)d_ws;
  bf16* xb  = (bf16*)ws;                               // 32 MB
  bf16* WiT = (bf16*)(ws + (size_t)M1 * K1 * 2);       //  8 MB
  bf16* Wpb = WiT + (size_t)N1q * K1;                  //  4 MB
  bf16* H   = Wpb + (size_t)N2 * K2;                   // 32 MB
  bf16* Wx = (bf16*)d_out;  // 134 MB Wx_rec[n][t][g][d][b]; dead before gemm_out

  cast_f32_bf16<<<(M1 * K1 / 4 + 255) / 256, 256, 0, stream>>>(x_emb, xb, M1 * K1 / 4);
  transpose_cast<<<dim3(N1q / 32, K1 / 32), 256, 0, stream>>>(W_in, WiT, K1, N1q);
  cast_f32_bf16<<<(N2 * K2 / 4 + 255) / 256, 256, 0, stream>>>(W_prj, Wpb, N2 * K2 / 4);

  gemm_bt<2><<<dim3(N1q / 128, M1 / 128), 256, 0, stream>>>(
      xb, WiT, (void*)Wx, bias, K1, N1q);

  lstm_mfma<<<dim3(Nq), 512, 0, stream>>>(Wx, R, H);

  gemm_bt<0><<<dim3(N2 / 128, M1 / 128), 256, 0, stream>>>(
      H, Wpb, d_out, b_prj, K2, N2);
}

// Round 12
// 955.080 us; speedup vs baseline: 2.0191x; 1.5675x over previous
//
#include <hip/hip_runtime.h>
#include <hip/hip_bf16.h>

#define DEV __device__ __forceinline__

using bf16 = __hip_bfloat16;
typedef __attribute__((ext_vector_type(8))) short short8v;  // 8 bf16 = 4 VGPRs
typedef __attribute__((ext_vector_type(4))) float f32x4;

constexpr int Bq = 16, Tq = 1024, Eq = 1024, Gq = 4, Nq = 8, Dq = 128, Vq = 2048;
constexpr int M1 = Bq * Tq;        // 16384
constexpr int N1q = Gq * Nq * Dq;  // 4096
constexpr int K1 = Eq;             // 1024
constexpr int K2 = Nq * Dq;        // 1024
constexpr int N2 = Vq;             // 2048

DEV unsigned short bfu(float x) {
  union { bf16 h; unsigned short u; } cv;
  cv.h = __float2bfloat16(x);
  return cv.u;
}

DEV float rcp_(float x) { return __builtin_amdgcn_rcpf(x); }
DEV float sigm(float x) { return rcp_(1.0f + __expf(-x)); }
DEV float tanh_(float x) { return fmaf(2.0f, rcp_(1.0f + __expf(-2.0f * x)), -1.0f); }

// async global->LDS, 16B per lane; LDS dest is wave-uniform base + lane*16
#define GLD16(gp, lp)                                                       \
  __builtin_amdgcn_global_load_lds(                                        \
      (const __attribute__((address_space(1))) void*)(gp),                 \
      (__attribute__((address_space(3))) void*)(lp), 16, 0, 0)

// ---------------------------------------------------------------------------
// Prep kernels: casts + transpose-cast
// ---------------------------------------------------------------------------
__global__ __launch_bounds__(256) void cast_f32_bf16(const float* __restrict__ s,
                                                     bf16* __restrict__ d, int n4) {
  const int i = blockIdx.x * 256 + threadIdx.x;
  if (i >= n4) return;
  const float4 v = ((const float4*)s)[i];
  ushort4 u;
  u.x = bfu(v.x); u.y = bfu(v.y); u.z = bfu(v.z); u.w = bfu(v.w);
  ((ushort4*)d)[i] = u;
}

// s: [SK][SN] f32 row-major  ->  d: [SN][SK] bf16 row-major
__global__ __launch_bounds__(256) void transpose_cast(const float* __restrict__ s,
                                                      bf16* __restrict__ d,
                                                      int SK, int SN) {
  __shared__ float t[32][33];
  const int n0 = blockIdx.x * 32, k0 = blockIdx.y * 32;
  const int tx = threadIdx.x & 31, ty = threadIdx.x >> 5;  // ty: 0..7
#pragma unroll
  for (int i = 0; i < 32; i += 8)
    t[ty + i][tx] = s[(size_t)(k0 + ty + i) * SN + n0 + tx];
  __syncthreads();
#pragma unroll
  for (int i = 0; i < 32; i += 8)
    d[(size_t)(n0 + ty + i) * SK + k0 + tx] = __float2bfloat16(t[tx][ty + i]);
}

// ---------------------------------------------------------------------------
// bf16 MFMA GEMM, m97 structure: C[M,N] = A[M,K] @ Bt[N,K]^T
// MODE 0: f32 out + bias.
// MODE 2: bf16 out + bias folded, scatter to Wx_rec[n][bq][t][d][b4][g4].
// ---------------------------------------------------------------------------
template <int MODE>
__global__ __launch_bounds__(256) void gemm_bt(const bf16* __restrict__ A,
                                               const bf16* __restrict__ Bt,
                                               void* __restrict__ Cout,
                                               const float* __restrict__ bp,
                                               int K, int N) {
  __shared__ bf16 As[128 * 32];
  __shared__ bf16 Bs[128 * 32];
  const int m0 = blockIdx.y * 128, n0 = blockIdx.x * 128;
  const int tid = threadIdx.x;
  const int lane = tid & 63, w = tid >> 6;
  const int wm = w >> 1, wn = w & 1;

  const int srow = lane >> 2, scol = (lane & 3) * 8;
  const int ca = w * 2;
  const bf16* Ag0 = A + (size_t)(m0 + ca * 16 + srow) * K + scol;
  const bf16* Ag1 = Ag0 + (size_t)16 * K;
  const bf16* Bg0 = Bt + (size_t)(n0 + ca * 16 + srow) * K + scol;
  const bf16* Bg1 = Bg0 + (size_t)16 * K;
  bf16* Al0 = As + ca * 512;
  bf16* Al1 = Al0 + 512;
  bf16* Bl0 = Bs + ca * 512;
  bf16* Bl1 = Bl0 + 512;

  f32x4 acc[4][4] = {};

  const int rr = lane & 15;
  const int kb = (lane >> 4) * 8;

  for (int k0 = 0; k0 < K; k0 += 32) {
    GLD16(Ag0 + k0, Al0);
    GLD16(Ag1 + k0, Al1);
    GLD16(Bg0 + k0, Bl0);
    GLD16(Bg1 + k0, Bl1);
    __syncthreads();
    short8v af[4], bfr[4];
#pragma unroll
    for (int i = 0; i < 4; ++i) {
      af[i]  = *(const short8v*)&As[(wm * 64 + i * 16 + rr) * 32 + kb];
      bfr[i] = *(const short8v*)&Bs[(wn * 64 + i * 16 + rr) * 32 + kb];
    }
#pragma unroll
    for (int i = 0; i < 4; ++i)
#pragma unroll
      for (int j = 0; j < 4; ++j)
        acc[i][j] = __builtin_amdgcn_mfma_f32_16x16x32_bf16(af[i], bfr[j], acc[i][j], 0, 0, 0);
    __syncthreads();
  }

  const int crow = (lane >> 4) * 4, ccol = lane & 15;
  if constexpr (MODE == 2) {
    // col=(g,nn,dd); row=(b16,t). bias folded (f32 add before bf16 round).
    // Wx_rec idx = nn<<23 | bq<<21 | t*2048 | dd*16 | b4*4 | g
    bf16* C = (bf16*)Cout;
#pragma unroll
    for (int i = 0; i < 4; ++i)
#pragma unroll
      for (int j = 0; j < 4; ++j) {
        const int col = n0 + wn * 64 + j * 16 + ccol;
        const int g = col >> 10, nn = (col >> 7) & 7, dd = col & 127;
        const float bvj = bp[(g * 8 + nn) * 128 + dd];
#pragma unroll
        for (int jj = 0; jj < 4; ++jj) {
          const int row = m0 + wm * 64 + i * 16 + crow + jj;
          const int b16 = row >> 10, t = row & 1023;
          const int bq = b16 >> 2, b4 = b16 & 3;
          const size_t idx = ((size_t)nn << 23) + ((size_t)bq << 21) +
                             (size_t)t * 2048 + dd * 16 + b4 * 4 + g;
          C[idx] = __float2bfloat16(acc[i][j][jj] + bvj);
        }
      }
  } else {
    float* C = (float*)Cout;
    float bv[4];
#pragma unroll
    for (int j = 0; j < 4; ++j) bv[j] = bp[n0 + wn * 64 + j * 16 + ccol];
#pragma unroll
    for (int i = 0; i < 4; ++i)
#pragma unroll
      for (int j = 0; j < 4; ++j) {
        const size_t base =
            (size_t)(m0 + wm * 64 + i * 16 + crow) * N + (n0 + wn * 64 + j * 16 + ccol);
#pragma unroll
        for (int jj = 0; jj < 4; ++jj)
          C[base + (size_t)jj * N] = acc[i][j][jj] + bv[j];
      }
  }
}

// ---------------------------------------------------------------------------
// LSTM recurrence, v12 = v11 with the use-after-overwrite FIXED:
// capture wxr[u] into a local BEFORE the t+4 prefetch overwrites the slot
// (v11 added wx AFTER the prefetch -> every step used wx from t+4).
// Structure: 32 WGs = (head n, batch-quad bq), 4 chains each, 8 waves.
// gates^T[512 gd][16 cols] = R_n[512x128] @ h^T[128x(4b x4 copies)].
// Lane (lg,lc), tile ci=lc>>2: site (b=lc&3, d=16w+4*ci+lg); acc elements
// jj = the 4 gates. 1 activation site per lane, no shuffles.
// ---------------------------------------------------------------------------
__global__ __launch_bounds__(512) void lstm_mfma(const bf16* __restrict__ Wx,
                                                 const float* __restrict__ R,
                                                 bf16* __restrict__ h_all) {
  const int bid = blockIdx.x;
  const int n = bid & 7, bq = bid >> 3;
  const int tid = threadIdx.x;
  const int w = tid >> 6, lane = tid & 63;
  const int lg = lane >> 4, lc = lane & 15;
  const int bloc = lc & 3;     // local batch 0..3
  const int ci = lc >> 2;      // selected tile index
  const int dsite = 16 * w + 4 * ci + lg;  // this lane's site d

  // A fragments (R): tile tau row lc -> gd = 64w+16*tau+lc; k = 32kf+8lg+j
  short8v Af[4][4];
#pragma unroll
  for (int tau = 0; tau < 4; ++tau) {
    const int gd = 64 * w + 16 * tau + lc;
    const int g = gd & 3, d = gd >> 2;
    const float* rbase = R + ((size_t)(g * 8 + n) * 128 + d) * 128;
#pragma unroll
    for (int kf = 0; kf < 4; ++kf) {
      const float* rp = rbase + 32 * kf + 8 * lg;
      const float4 r0 = *(const float4*)rp;
      const float4 r1 = *(const float4*)(rp + 4);
      short8v bv;
      bv[0] = (short)bfu(r0.x); bv[1] = (short)bfu(r0.y);
      bv[2] = (short)bfu(r0.z); bv[3] = (short)bfu(r0.w);
      bv[4] = (short)bfu(r1.x); bv[5] = (short)bfu(r1.y);
      bv[6] = (short)bfu(r1.z); bv[7] = (short)bfu(r1.w);
      Af[tau][kf] = bv;
    }
  }

  // h LDS: [dbuf][b(4)][144] ushorts (pitch 288B)
  __shared__ __align__(16) unsigned short hl[2][4][144];
  for (int i = tid; i < 4 * 144; i += 512) (&hl[0][0][0])[i] = 0;  // bf16 0.0
  __syncthreads();

  // wx: idx = n<<23 | bq<<21 | t*2048 | d*16 | b4*4 | g  (g contiguous)
  const bf16* wxb = Wx + ((size_t)n << 23) + ((size_t)bq << 21) + dsite * 16 + bloc * 4;
  // h_all[b*1024+t][n*128+d]
  bf16* hout = h_all + ((size_t)(bq * 4 + bloc) << 20) + n * 128 + dsite;

  // 4-deep static prefetch: one ushort4 (4 gates) per step
  ushort4 wxr[4];
#pragma unroll
  for (int u = 0; u < 4; ++u)
    wxr[u] = *(const ushort4*)(wxb + (size_t)u * 2048);

  float c = 0.f;

  for (int t0 = 0; t0 < Tq; t0 += 4) {
#pragma unroll
    for (int u = 0; u < 4; ++u) {
      const int t = t0 + u;
      // B fragments: col lc -> h row (lc&3), k = 32kf+8lg+j
      const unsigned short* hb = &hl[t & 1][0][0];
      short8v Bf[4];
#pragma unroll
      for (int kf = 0; kf < 4; ++kf)
        Bf[kf] = *(const short8v*)(hb + bloc * 144 + kf * 32 + lg * 8);

      // *** FIX: capture this step's wx BEFORE the slot is overwritten ***
      const ushort4 wxc = wxr[u];

      // 4 independent MFMA tile chains, C-in = 0
      f32x4 acc[4];
#pragma unroll
      for (int tau = 0; tau < 4; ++tau) {
        acc[tau][0] = 0.f; acc[tau][1] = 0.f; acc[tau][2] = 0.f; acc[tau][3] = 0.f;
      }
#pragma unroll
      for (int kf = 0; kf < 4; ++kf)
#pragma unroll
        for (int tau = 0; tau < 4; ++tau)
          acc[tau] = __builtin_amdgcn_mfma_f32_16x16x32_bf16(Af[tau][kf], Bf[kf], acc[tau], 0, 0, 0);

      // prefetch wx for step t+4 into the SAME static slot (now safe)
      {
        const int tp = (t + 4 < Tq) ? (t + 4) : (Tq - 1);
        wxr[u] = *(const ushort4*)(wxb + (size_t)tp * 2048);
      }

      // extract this lane's site (tile ci) + add wx; elements = gates i,f,z,o
      float pre0 = (ci & 2) ? ((ci & 1) ? acc[3][0] : acc[2][0])
                            : ((ci & 1) ? acc[1][0] : acc[0][0]);
      float pre1 = (ci & 2) ? ((ci & 1) ? acc[3][1] : acc[2][1])
                            : ((ci & 1) ? acc[1][1] : acc[0][1]);
      float pre2 = (ci & 2) ? ((ci & 1) ? acc[3][2] : acc[2][2])
                            : ((ci & 1) ? acc[1][2] : acc[0][2]);
      float pre3 = (ci & 2) ? ((ci & 1) ? acc[3][3] : acc[2][3])
                            : ((ci & 1) ? acc[1][3] : acc[0][3]);
      pre0 += __uint_as_float((unsigned)wxc.x << 16);
      pre1 += __uint_as_float((unsigned)wxc.y << 16);
      pre2 += __uint_as_float((unsigned)wxc.z << 16);
      pre3 += __uint_as_float((unsigned)wxc.w << 16);

      const float i_ = sigm(pre0);
      const float f_ = sigm(pre1);
      const float z_ = tanh_(pre2);
      const float o_ = sigm(pre3);
      c = f_ * c + i_ * z_;
      const float h = o_ * tanh_(c);
      const bf16 h16 = __float2bfloat16(h);

      hl[(t + 1) & 1][bloc][dsite] = ((const unsigned short*)&h16)[0];
      hout[(size_t)t << 10] = h16;

      // barrier WITHOUT vmcnt drain: only LDS visibility needed.
      __builtin_amdgcn_sched_barrier(0);
      asm volatile("s_waitcnt lgkmcnt(0)" ::: "memory");
      __builtin_amdgcn_sched_barrier(0);
      __builtin_amdgcn_s_barrier();
      __builtin_amdgcn_sched_barrier(0);
    }
  }
}

// ---------------------------------------------------------------------------
extern "C" void kernel_launch(void* const* d_in, const int* in_sizes, int n_in,
                              void* d_out, int out_size, void* d_ws, size_t ws_size,
                              hipStream_t stream) {
  const float* x_emb = (const float*)d_in[0];  // [16,1024,1024]
  const float* W_in  = (const float*)d_in[1];  // [1024,4096]
  const float* R     = (const float*)d_in[2];  // [4,8,128,128]
  const float* bias  = (const float*)d_in[3];  // [4,8,128]
  const float* W_prj = (const float*)d_in[4];  // [2048,1024]
  const float* b_prj = (const float*)d_in[5];  // [2048]

  char* ws = (char*)d_ws;
  bf16* xb  = (bf16*)ws;                               // 32 MB
  bf16* WiT = (bf16*)(ws + (size_t)M1 * K1 * 2);       //  8 MB
  bf16* Wpb = WiT + (size_t)N1q * K1;                  //  4 MB
  bf16* H   = Wpb + (size_t)N2 * K2;                   // 32 MB
  bf16* Wx = (bf16*)d_out;  // 134 MB Wx_rec; dead before gemm_out

  cast_f32_bf16<<<(M1 * K1 / 4 + 255) / 256, 256, 0, stream>>>(x_emb, xb, M1 * K1 / 4);
  transpose_cast<<<dim3(N1q / 32, K1 / 32), 256, 0, stream>>>(W_in, WiT, K1, N1q);
  cast_f32_bf16<<<(N2 * K2 / 4 + 255) / 256, 256, 0, stream>>>(W_prj, Wpb, N2 * K2 / 4);

  gemm_bt<2><<<dim3(N1q / 128, M1 / 128), 256, 0, stream>>>(
      xb, WiT, (void*)Wx, bias, K1, N1q);

  lstm_mfma<<<dim3(32), 512, 0, stream>>>(Wx, R, H);

  gemm_bt<0><<<dim3(N2 / 128, M1 / 128), 256, 0, stream>>>(
      H, Wpb, d_out, b_prj, K2, N2);
}

// Round 13
// 821.285 us; speedup vs baseline: 2.3481x; 1.1629x over previous
//
#include <hip/hip_runtime.h>
#include <hip/hip_bf16.h>

#define DEV __device__ __forceinline__

using bf16 = __hip_bfloat16;
typedef __attribute__((ext_vector_type(8))) short short8v;  // 8 bf16 = 4 VGPRs
typedef __attribute__((ext_vector_type(4))) float f32x4;

constexpr int Bq = 16, Tq = 1024, Eq = 1024, Gq = 4, Nq = 8, Dq = 128, Vq = 2048;
constexpr int M1 = Bq * Tq;        // 16384
constexpr int N1q = Gq * Nq * Dq;  // 4096
constexpr int K1 = Eq;             // 1024
constexpr int K2 = Nq * Dq;        // 1024
constexpr int N2 = Vq;             // 2048

DEV unsigned short bfu(float x) {
  union { bf16 h; unsigned short u; } cv;
  cv.h = __float2bfloat16(x);
  return cv.u;
}

DEV float rcp_(float x) { return __builtin_amdgcn_rcpf(x); }
DEV float sigm(float x) { return rcp_(1.0f + __expf(-x)); }
DEV float tanh_(float x) { return fmaf(2.0f, rcp_(1.0f + __expf(-2.0f * x)), -1.0f); }

// async global->LDS, 16B per lane; LDS dest is wave-uniform base + lane*16
#define GLD16(gp, lp)                                                       \
  __builtin_amdgcn_global_load_lds(                                        \
      (const __attribute__((address_space(1))) void*)(gp),                 \
      (__attribute__((address_space(3))) void*)(lp), 16, 0, 0)

// ---------------------------------------------------------------------------
// Prep kernels: casts + transpose-cast
// ---------------------------------------------------------------------------
__global__ __launch_bounds__(256) void cast_f32_bf16(const float* __restrict__ s,
                                                     bf16* __restrict__ d, int n4) {
  const int i = blockIdx.x * 256 + threadIdx.x;
  if (i >= n4) return;
  const float4 v = ((const float4*)s)[i];
  ushort4 u;
  u.x = bfu(v.x); u.y = bfu(v.y); u.z = bfu(v.z); u.w = bfu(v.w);
  ((ushort4*)d)[i] = u;
}

// s: [SK][SN] f32 row-major  ->  d: [SN][SK] bf16 row-major
__global__ __launch_bounds__(256) void transpose_cast(const float* __restrict__ s,
                                                      bf16* __restrict__ d,
                                                      int SK, int SN) {
  __shared__ float t[32][33];
  const int n0 = blockIdx.x * 32, k0 = blockIdx.y * 32;
  const int tx = threadIdx.x & 31, ty = threadIdx.x >> 5;  // ty: 0..7
#pragma unroll
  for (int i = 0; i < 32; i += 8)
    t[ty + i][tx] = s[(size_t)(k0 + ty + i) * SN + n0 + tx];
  __syncthreads();
#pragma unroll
  for (int i = 0; i < 32; i += 8)
    d[(size_t)(n0 + ty + i) * SK + k0 + tx] = __float2bfloat16(t[tx][ty + i]);
}

// ---------------------------------------------------------------------------
// bf16 MFMA GEMM, m97 structure: C[M,N] = A[M,K] @ Bt[N,K]^T
// MODE 0: f32 out + bias.
// MODE 2: bf16 out + bias folded, NATURAL row-major layout (coalesced).
// ---------------------------------------------------------------------------
template <int MODE>
__global__ __launch_bounds__(256) void gemm_bt(const bf16* __restrict__ A,
                                               const bf16* __restrict__ Bt,
                                               void* __restrict__ Cout,
                                               const float* __restrict__ bp,
                                               int K, int N) {
  __shared__ bf16 As[128 * 32];
  __shared__ bf16 Bs[128 * 32];
  const int m0 = blockIdx.y * 128, n0 = blockIdx.x * 128;
  const int tid = threadIdx.x;
  const int lane = tid & 63, w = tid >> 6;
  const int wm = w >> 1, wn = w & 1;

  const int srow = lane >> 2, scol = (lane & 3) * 8;
  const int ca = w * 2;
  const bf16* Ag0 = A + (size_t)(m0 + ca * 16 + srow) * K + scol;
  const bf16* Ag1 = Ag0 + (size_t)16 * K;
  const bf16* Bg0 = Bt + (size_t)(n0 + ca * 16 + srow) * K + scol;
  const bf16* Bg1 = Bg0 + (size_t)16 * K;
  bf16* Al0 = As + ca * 512;
  bf16* Al1 = Al0 + 512;
  bf16* Bl0 = Bs + ca * 512;
  bf16* Bl1 = Bl0 + 512;

  f32x4 acc[4][4] = {};

  const int rr = lane & 15;
  const int kb = (lane >> 4) * 8;

  for (int k0 = 0; k0 < K; k0 += 32) {
    GLD16(Ag0 + k0, Al0);
    GLD16(Ag1 + k0, Al1);
    GLD16(Bg0 + k0, Bl0);
    GLD16(Bg1 + k0, Bl1);
    __syncthreads();
    short8v af[4], bfr[4];
#pragma unroll
    for (int i = 0; i < 4; ++i) {
      af[i]  = *(const short8v*)&As[(wm * 64 + i * 16 + rr) * 32 + kb];
      bfr[i] = *(const short8v*)&Bs[(wn * 64 + i * 16 + rr) * 32 + kb];
    }
#pragma unroll
    for (int i = 0; i < 4; ++i)
#pragma unroll
      for (int j = 0; j < 4; ++j)
        acc[i][j] = __builtin_amdgcn_mfma_f32_16x16x32_bf16(af[i], bfr[j], acc[i][j], 0, 0, 0);
    __syncthreads();
  }

  const int crow = (lane >> 4) * 4, ccol = lane & 15;
  if constexpr (MODE == 2) {
    // natural row-major bf16: C[row][col], col = g*1024+n*128+d.
    // bias index == col. Coalesced: 16 lanes x 2B contiguous per store.
    bf16* C = (bf16*)Cout;
#pragma unroll
    for (int i = 0; i < 4; ++i)
#pragma unroll
      for (int j = 0; j < 4; ++j) {
        const int col = n0 + wn * 64 + j * 16 + ccol;
        const float bvj = bp[col];
        const size_t base = (size_t)(m0 + wm * 64 + i * 16 + crow) * N + col;
#pragma unroll
        for (int jj = 0; jj < 4; ++jj)
          C[base + (size_t)jj * N] = __float2bfloat16(acc[i][j][jj] + bvj);
      }
  } else {
    float* C = (float*)Cout;
    float bv[4];
#pragma unroll
    for (int j = 0; j < 4; ++j) bv[j] = bp[n0 + wn * 64 + j * 16 + ccol];
#pragma unroll
    for (int i = 0; i < 4; ++i)
#pragma unroll
      for (int j = 0; j < 4; ++j) {
        const size_t base =
            (size_t)(m0 + wm * 64 + i * 16 + crow) * N + (n0 + wn * 64 + j * 16 + ccol);
#pragma unroll
        for (int jj = 0; jj < 4; ++jj)
          C[base + (size_t)jj * N] = acc[i][j][jj] + bv[j];
      }
  }
}

// ---------------------------------------------------------------------------
// LSTM recurrence, v13 = v12 structure, wx read from NATURAL layout.
// 32 WGs = (head n, batch-quad bq), 4 chains each, 8 waves.
// gates^T[512 gd][16 cols] = R_n[512x128] @ h^T[128x(4b x4 copies)].
// Lane (lg,lc), tile ci=lc>>2: site (b=lc&3, d=16w+4*ci+lg); acc elements
// jj = the 4 gates. 1 activation site per lane, no shuffles.
// wx: natural [b*1024+t][g*1024+n*128+d] -> 4 strided ushort loads/step
// (r4/r5 evidence: 4 loads/step ~ 1 load/step; GEMM store coalescing is
// what the packed layout cost us: +229 us).
// ---------------------------------------------------------------------------
__global__ __launch_bounds__(512) void lstm_mfma(const bf16* __restrict__ Wx,
                                                 const float* __restrict__ R,
                                                 bf16* __restrict__ h_all) {
  const int bid = blockIdx.x;
  const int n = bid & 7, bq = bid >> 3;
  const int tid = threadIdx.x;
  const int w = tid >> 6, lane = tid & 63;
  const int lg = lane >> 4, lc = lane & 15;
  const int bloc = lc & 3;     // local batch 0..3
  const int ci = lc >> 2;      // selected tile index
  const int dsite = 16 * w + 4 * ci + lg;  // this lane's site d

  // A fragments (R): tile tau row lc -> gd = 64w+16*tau+lc; k = 32kf+8lg+j
  short8v Af[4][4];
#pragma unroll
  for (int tau = 0; tau < 4; ++tau) {
    const int gd = 64 * w + 16 * tau + lc;
    const int g = gd & 3, d = gd >> 2;
    const float* rbase = R + ((size_t)(g * 8 + n) * 128 + d) * 128;
#pragma unroll
    for (int kf = 0; kf < 4; ++kf) {
      const float* rp = rbase + 32 * kf + 8 * lg;
      const float4 r0 = *(const float4*)rp;
      const float4 r1 = *(const float4*)(rp + 4);
      short8v bv;
      bv[0] = (short)bfu(r0.x); bv[1] = (short)bfu(r0.y);
      bv[2] = (short)bfu(r0.z); bv[3] = (short)bfu(r0.w);
      bv[4] = (short)bfu(r1.x); bv[5] = (short)bfu(r1.y);
      bv[6] = (short)bfu(r1.z); bv[7] = (short)bfu(r1.w);
      Af[tau][kf] = bv;
    }
  }

  // h LDS: [dbuf][b(4)][144] ushorts (pitch 288B)
  __shared__ __align__(16) unsigned short hl[2][4][144];
  for (int i = tid; i < 4 * 144; i += 512) (&hl[0][0][0])[i] = 0;  // bf16 0.0
  __syncthreads();

  // wx natural: Wx[(b*1024+t)*4096 + g*1024 + n*128 + d]
  const bf16* wxg =
      Wx + ((size_t)(bq * 4 + bloc) << 10) * 4096 + n * 128 + dsite;
  // h_all[b*1024+t][n*128+d]
  bf16* hout = h_all + ((size_t)(bq * 4 + bloc) << 20) + n * 128 + dsite;

  // 4-deep static prefetch: 4 gate ushorts per step (stride 1024 el)
  unsigned short wxr[4][4];
#pragma unroll
  for (int u = 0; u < 4; ++u)
#pragma unroll
    for (int g = 0; g < 4; ++g)
      wxr[u][g] = *(const unsigned short*)(wxg + (size_t)u * 4096 + g * 1024);

  float c = 0.f;

  for (int t0 = 0; t0 < Tq; t0 += 4) {
#pragma unroll
    for (int u = 0; u < 4; ++u) {
      const int t = t0 + u;
      // B fragments: col lc -> h row (lc&3), k = 32kf+8lg+j
      const unsigned short* hb = &hl[t & 1][0][0];
      short8v Bf[4];
#pragma unroll
      for (int kf = 0; kf < 4; ++kf)
        Bf[kf] = *(const short8v*)(hb + bloc * 144 + kf * 32 + lg * 8);

      // capture this step's wx BEFORE the slot is overwritten (r11 lesson)
      const unsigned short wxc0 = wxr[u][0], wxc1 = wxr[u][1];
      const unsigned short wxc2 = wxr[u][2], wxc3 = wxr[u][3];

      // 4 independent MFMA tile chains, C-in = 0
      f32x4 acc[4];
#pragma unroll
      for (int tau = 0; tau < 4; ++tau) {
        acc[tau][0] = 0.f; acc[tau][1] = 0.f; acc[tau][2] = 0.f; acc[tau][3] = 0.f;
      }
#pragma unroll
      for (int kf = 0; kf < 4; ++kf)
#pragma unroll
        for (int tau = 0; tau < 4; ++tau)
          acc[tau] = __builtin_amdgcn_mfma_f32_16x16x32_bf16(Af[tau][kf], Bf[kf], acc[tau], 0, 0, 0);

      // prefetch wx for step t+4 into the SAME static slot (safe now)
      {
        const int tp = (t + 4 < Tq) ? (t + 4) : (Tq - 1);
#pragma unroll
        for (int g = 0; g < 4; ++g)
          wxr[u][g] = *(const unsigned short*)(wxg + (size_t)tp * 4096 + g * 1024);
      }

      // extract this lane's site (tile ci) + add wx; elements = gates i,f,z,o
      float pre0 = (ci & 2) ? ((ci & 1) ? acc[3][0] : acc[2][0])
                            : ((ci & 1) ? acc[1][0] : acc[0][0]);
      float pre1 = (ci & 2) ? ((ci & 1) ? acc[3][1] : acc[2][1])
                            : ((ci & 1) ? acc[1][1] : acc[0][1]);
      float pre2 = (ci & 2) ? ((ci & 1) ? acc[3][2] : acc[2][2])
                            : ((ci & 1) ? acc[1][2] : acc[0][2]);
      float pre3 = (ci & 2) ? ((ci & 1) ? acc[3][3] : acc[2][3])
                            : ((ci & 1) ? acc[1][3] : acc[0][3]);
      pre0 += __uint_as_float((unsigned)wxc0 << 16);
      pre1 += __uint_as_float((unsigned)wxc1 << 16);
      pre2 += __uint_as_float((unsigned)wxc2 << 16);
      pre3 += __uint_as_float((unsigned)wxc3 << 16);

      const float i_ = sigm(pre0);
      const float f_ = sigm(pre1);
      const float z_ = tanh_(pre2);
      const float o_ = sigm(pre3);
      c = f_ * c + i_ * z_;
      const float h = o_ * tanh_(c);
      const bf16 h16 = __float2bfloat16(h);

      hl[(t + 1) & 1][bloc][dsite] = ((const unsigned short*)&h16)[0];
      hout[(size_t)t << 10] = h16;

      // barrier WITHOUT vmcnt drain: only LDS visibility needed.
      __builtin_amdgcn_sched_barrier(0);
      asm volatile("s_waitcnt lgkmcnt(0)" ::: "memory");
      __builtin_amdgcn_sched_barrier(0);
      __builtin_amdgcn_s_barrier();
      __builtin_amdgcn_sched_barrier(0);
    }
  }
}

// ---------------------------------------------------------------------------
extern "C" void kernel_launch(void* const* d_in, const int* in_sizes, int n_in,
                              void* d_out, int out_size, void* d_ws, size_t ws_size,
                              hipStream_t stream) {
  const float* x_emb = (const float*)d_in[0];  // [16,1024,1024]
  const float* W_in  = (const float*)d_in[1];  // [1024,4096]
  const float* R     = (const float*)d_in[2];  // [4,8,128,128]
  const float* bias  = (const float*)d_in[3];  // [4,8,128]
  const float* W_prj = (const float*)d_in[4];  // [2048,1024]
  const float* b_prj = (const float*)d_in[5];  // [2048]

  char* ws = (char*)d_ws;
  bf16* xb  = (bf16*)ws;                               // 32 MB
  bf16* WiT = (bf16*)(ws + (size_t)M1 * K1 * 2);       //  8 MB
  bf16* Wpb = WiT + (size_t)N1q * K1;                  //  4 MB
  bf16* H   = Wpb + (size_t)N2 * K2;                   // 32 MB
  bf16* Wx = (bf16*)d_out;  // 134 MB natural [b,t][g,n,d]; dead before gemm_out

  cast_f32_bf16<<<(M1 * K1 / 4 + 255) / 256, 256, 0, stream>>>(x_emb, xb, M1 * K1 / 4);
  transpose_cast<<<dim3(N1q / 32, K1 / 32), 256, 0, stream>>>(W_in, WiT, K1, N1q);
  cast_f32_bf16<<<(N2 * K2 / 4 + 255) / 256, 256, 0, stream>>>(W_prj, Wpb, N2 * K2 / 4);

  gemm_bt<2><<<dim3(N1q / 128, M1 / 128), 256, 0, stream>>>(
      xb, WiT, (void*)Wx, bias, K1, N1q);

  lstm_mfma<<<dim3(32), 512, 0, stream>>>(Wx, R, H);

  gemm_bt<0><<<dim3(N2 / 128, M1 / 128), 256, 0, stream>>>(
      H, Wpb, d_out, b_prj, K2, N2);
}

// Round 14
// 792.913 us; speedup vs baseline: 2.4321x; 1.0358x over previous
//
#include <hip/hip_runtime.h>
#include <hip/hip_bf16.h>

#define DEV __device__ __forceinline__

using bf16 = __hip_bfloat16;
typedef __attribute__((ext_vector_type(8))) short short8v;  // 8 bf16 = 4 VGPRs
typedef __attribute__((ext_vector_type(4))) float f32x4;

constexpr int Bq = 16, Tq = 1024, Eq = 1024, Gq = 4, Nq = 8, Dq = 128, Vq = 2048;
constexpr int M1 = Bq * Tq;        // 16384
constexpr int N1q = Gq * Nq * Dq;  // 4096
constexpr int K1 = Eq;             // 1024
constexpr int K2 = Nq * Dq;        // 1024
constexpr int N2 = Vq;             // 2048

DEV unsigned short bfu(float x) {
  union { bf16 h; unsigned short u; } cv;
  cv.h = __float2bfloat16(x);
  return cv.u;
}

DEV float rcp_(float x) { return __builtin_amdgcn_rcpf(x); }
DEV float sigm(float x) { return rcp_(1.0f + __expf(-x)); }
DEV float tanh_(float x) { return fmaf(2.0f, rcp_(1.0f + __expf(-2.0f * x)), -1.0f); }

// async global->LDS, 16B per lane; LDS dest is wave-uniform base + lane*16
#define GLD16(gp, lp)                                                       \
  __builtin_amdgcn_global_load_lds(                                        \
      (const __attribute__((address_space(1))) void*)(gp),                 \
      (__attribute__((address_space(3))) void*)(lp), 16, 0, 0)

// ---------------------------------------------------------------------------
// Prep kernels
// ---------------------------------------------------------------------------
__global__ __launch_bounds__(256) void cast_f32_bf16(const float* __restrict__ s,
                                                     bf16* __restrict__ d, int n4) {
  const int i = blockIdx.x * 256 + threadIdx.x;
  if (i >= n4) return;
  const float4 v = ((const float4*)s)[i];
  ushort4 u;
  u.x = bfu(v.x); u.y = bfu(v.y); u.z = bfu(v.z); u.w = bfu(v.w);
  ((ushort4*)d)[i] = u;
}

// W_in[k][c] f32 (c = g*1024+n*128+dd) -> WiT_perm[n*512 + dd*4 + g][k] bf16.
// Row permutation folded into the transpose (zero extra cost).
__global__ __launch_bounds__(256) void transpose_cast_perm(const float* __restrict__ s,
                                                           bf16* __restrict__ d,
                                                           int SK, int SN) {
  __shared__ float t[32][33];
  const int n0 = blockIdx.x * 32, k0 = blockIdx.y * 32;
  const int tx = threadIdx.x & 31, ty = threadIdx.x >> 5;  // ty: 0..7
#pragma unroll
  for (int i = 0; i < 32; i += 8)
    t[ty + i][tx] = s[(size_t)(k0 + ty + i) * SN + n0 + tx];
  __syncthreads();
#pragma unroll
  for (int i = 0; i < 32; i += 8) {
    const int c = n0 + ty + i;                 // original W_in column
    const int g = c >> 10, n = (c >> 7) & 7, dd = c & 127;
    const int rp = n * 512 + dd * 4 + g;       // permuted row
    d[(size_t)rp * SK + k0 + tx] = __float2bfloat16(t[tx][ty + i]);
  }
}

// ---------------------------------------------------------------------------
// bf16 MFMA GEMM, m97 structure: C[M,N] = A[M,K] @ Bt[N,K]^T
// MODE 0: f32 out + bias (natural).
// MODE 3: bf16 out + bias folded, permuted-packed: B rows are WiT_perm
//   (pc = n*512 + dd*4 + g), output idx = ((b*8+n)*1024+t)*512 + (pc&511).
//   Same 16-lane x 32B store coalescing as the natural layout.
// ---------------------------------------------------------------------------
template <int MODE>
__global__ __launch_bounds__(256) void gemm_bt(const bf16* __restrict__ A,
                                               const bf16* __restrict__ Bt,
                                               void* __restrict__ Cout,
                                               const float* __restrict__ bp,
                                               int K, int N) {
  __shared__ bf16 As[128 * 32];
  __shared__ bf16 Bs[128 * 32];
  const int m0 = blockIdx.y * 128, n0 = blockIdx.x * 128;
  const int tid = threadIdx.x;
  const int lane = tid & 63, w = tid >> 6;
  const int wm = w >> 1, wn = w & 1;

  const int srow = lane >> 2, scol = (lane & 3) * 8;
  const int ca = w * 2;
  const bf16* Ag0 = A + (size_t)(m0 + ca * 16 + srow) * K + scol;
  const bf16* Ag1 = Ag0 + (size_t)16 * K;
  const bf16* Bg0 = Bt + (size_t)(n0 + ca * 16 + srow) * K + scol;
  const bf16* Bg1 = Bg0 + (size_t)16 * K;
  bf16* Al0 = As + ca * 512;
  bf16* Al1 = Al0 + 512;
  bf16* Bl0 = Bs + ca * 512;
  bf16* Bl1 = Bl0 + 512;

  f32x4 acc[4][4] = {};

  const int rr = lane & 15;
  const int kb = (lane >> 4) * 8;

  for (int k0 = 0; k0 < K; k0 += 32) {
    GLD16(Ag0 + k0, Al0);
    GLD16(Ag1 + k0, Al1);
    GLD16(Bg0 + k0, Bl0);
    GLD16(Bg1 + k0, Bl1);
    __syncthreads();
    short8v af[4], bfr[4];
#pragma unroll
    for (int i = 0; i < 4; ++i) {
      af[i]  = *(const short8v*)&As[(wm * 64 + i * 16 + rr) * 32 + kb];
      bfr[i] = *(const short8v*)&Bs[(wn * 64 + i * 16 + rr) * 32 + kb];
    }
#pragma unroll
    for (int i = 0; i < 4; ++i)
#pragma unroll
      for (int j = 0; j < 4; ++j)
        acc[i][j] = __builtin_amdgcn_mfma_f32_16x16x32_bf16(af[i], bfr[j], acc[i][j], 0, 0, 0);
    __syncthreads();
  }

  const int crow = (lane >> 4) * 4, ccol = lane & 15;
  if constexpr (MODE == 3) {
    // permuted col pc = n*512 + dd*4 + g; output row (b,t).
    bf16* C = (bf16*)Cout;
#pragma unroll
    for (int i = 0; i < 4; ++i)
#pragma unroll
      for (int j = 0; j < 4; ++j) {
        const int pc = n0 + wn * 64 + j * 16 + ccol;
        const int n = pc >> 9, gd = pc & 511;
        const int g = gd & 3, dd = gd >> 2;
        const float bvj = bp[(g * 8 + n) * 128 + dd];
#pragma unroll
        for (int jj = 0; jj < 4; ++jj) {
          const int row = m0 + wm * 64 + i * 16 + crow + jj;
          const int b = row >> 10, t = row & 1023;
          const size_t idx = (((size_t)(b * 8 + n) << 10) + t) * 512 + gd;
          C[idx] = __float2bfloat16(acc[i][j][jj] + bvj);
        }
      }
  } else {
    float* C = (float*)Cout;
    float bv[4];
#pragma unroll
    for (int j = 0; j < 4; ++j) bv[j] = bp[n0 + wn * 64 + j * 16 + ccol];
#pragma unroll
    for (int i = 0; i < 4; ++i)
#pragma unroll
      for (int j = 0; j < 4; ++j) {
        const size_t base =
            (size_t)(m0 + wm * 64 + i * 16 + crow) * N + (n0 + wn * 64 + j * 16 + ccol);
#pragma unroll
        for (int jj = 0; jj < 4; ++jj)
          C[base + (size_t)jj * N] = acc[i][j][jj] + bv[j];
      }
  }
}

// ---------------------------------------------------------------------------
// LSTM recurrence, v14 = v12 recurrence + packed wx [(b*8+n)*1024+t][d*4+g]:
// ONE ushort4 (8B) load per step (the proven 492us pattern), layout now
// produced coalesced by the permuted GEMM epilogue.
// 32 WGs = (head n, batch-quad bq), 4 chains each, 8 waves.
// Lane (lg,lc), tile ci=lc>>2: site (b=lc&3, d=16w+4*ci+lg); acc elements
// jj = the 4 gates. 1 activation site per lane, no shuffles.
// ---------------------------------------------------------------------------
__global__ __launch_bounds__(512) void lstm_mfma(const bf16* __restrict__ Wx,
                                                 const float* __restrict__ R,
                                                 bf16* __restrict__ h_all) {
  const int bid = blockIdx.x;
  const int n = bid & 7, bq = bid >> 3;
  const int tid = threadIdx.x;
  const int w = tid >> 6, lane = tid & 63;
  const int lg = lane >> 4, lc = lane & 15;
  const int bloc = lc & 3;     // local batch 0..3
  const int ci = lc >> 2;      // selected tile index
  const int dsite = 16 * w + 4 * ci + lg;  // this lane's site d

  // A fragments (R): tile tau row lc -> gd = 64w+16*tau+lc; k = 32kf+8lg+j
  short8v Af[4][4];
#pragma unroll
  for (int tau = 0; tau < 4; ++tau) {
    const int gd = 64 * w + 16 * tau + lc;
    const int g = gd & 3, d = gd >> 2;
    const float* rbase = R + ((size_t)(g * 8 + n) * 128 + d) * 128;
#pragma unroll
    for (int kf = 0; kf < 4; ++kf) {
      const float* rp = rbase + 32 * kf + 8 * lg;
      const float4 r0 = *(const float4*)rp;
      const float4 r1 = *(const float4*)(rp + 4);
      short8v bv;
      bv[0] = (short)bfu(r0.x); bv[1] = (short)bfu(r0.y);
      bv[2] = (short)bfu(r0.z); bv[3] = (short)bfu(r0.w);
      bv[4] = (short)bfu(r1.x); bv[5] = (short)bfu(r1.y);
      bv[6] = (short)bfu(r1.z); bv[7] = (short)bfu(r1.w);
      Af[tau][kf] = bv;
    }
  }

  // h LDS: [dbuf][b(4)][144] ushorts (pitch 288B)
  __shared__ __align__(16) unsigned short hl[2][4][144];
  for (int i = tid; i < 4 * 144; i += 512) (&hl[0][0][0])[i] = 0;  // bf16 0.0
  __syncthreads();

  // wx packed: Wx[((b*8+n)*1024+t)*512 + d*4 + g]
  const bf16* wxb =
      Wx + ((size_t)((bq * 4 + bloc) * 8 + n) << 10) * 512 + dsite * 4;
  // h_all[b*1024+t][n*128+d]
  bf16* hout = h_all + ((size_t)(bq * 4 + bloc) << 20) + n * 128 + dsite;

  // 4-deep static prefetch: one ushort4 (4 gates) per step
  ushort4 wxr[4];
#pragma unroll
  for (int u = 0; u < 4; ++u)
    wxr[u] = *(const ushort4*)(wxb + (size_t)u * 512);

  float c = 0.f;

  for (int t0 = 0; t0 < Tq; t0 += 4) {
#pragma unroll
    for (int u = 0; u < 4; ++u) {
      const int t = t0 + u;
      // B fragments: col lc -> h row (lc&3), k = 32kf+8lg+j
      const unsigned short* hb = &hl[t & 1][0][0];
      short8v Bf[4];
#pragma unroll
      for (int kf = 0; kf < 4; ++kf)
        Bf[kf] = *(const short8v*)(hb + bloc * 144 + kf * 32 + lg * 8);

      // capture this step's wx BEFORE the slot is overwritten (r11 lesson)
      const ushort4 wxc = wxr[u];

      // 4 independent MFMA tile chains, C-in = 0
      f32x4 acc[4];
#pragma unroll
      for (int tau = 0; tau < 4; ++tau) {
        acc[tau][0] = 0.f; acc[tau][1] = 0.f; acc[tau][2] = 0.f; acc[tau][3] = 0.f;
      }
#pragma unroll
      for (int kf = 0; kf < 4; ++kf)
#pragma unroll
        for (int tau = 0; tau < 4; ++tau)
          acc[tau] = __builtin_amdgcn_mfma_f32_16x16x32_bf16(Af[tau][kf], Bf[kf], acc[tau], 0, 0, 0);

      // prefetch wx for step t+4 into the SAME static slot (safe now)
      {
        const int tp = (t + 4 < Tq) ? (t + 4) : (Tq - 1);
        wxr[u] = *(const ushort4*)(wxb + (size_t)tp * 512);
      }

      // extract this lane's site (tile ci) + add wx; elements = gates i,f,z,o
      float pre0 = (ci & 2) ? ((ci & 1) ? acc[3][0] : acc[2][0])
                            : ((ci & 1) ? acc[1][0] : acc[0][0]);
      float pre1 = (ci & 2) ? ((ci & 1) ? acc[3][1] : acc[2][1])
                            : ((ci & 1) ? acc[1][1] : acc[0][1]);
      float pre2 = (ci & 2) ? ((ci & 1) ? acc[3][2] : acc[2][2])
                            : ((ci & 1) ? acc[1][2] : acc[0][2]);
      float pre3 = (ci & 2) ? ((ci & 1) ? acc[3][3] : acc[2][3])
                            : ((ci & 1) ? acc[1][3] : acc[0][3]);
      pre0 += __uint_as_float((unsigned)wxc.x << 16);
      pre1 += __uint_as_float((unsigned)wxc.y << 16);
      pre2 += __uint_as_float((unsigned)wxc.z << 16);
      pre3 += __uint_as_float((unsigned)wxc.w << 16);

      const float i_ = sigm(pre0);
      const float f_ = sigm(pre1);
      const float z_ = tanh_(pre2);
      const float o_ = sigm(pre3);
      c = f_ * c + i_ * z_;
      const float h = o_ * tanh_(c);
      const bf16 h16 = __float2bfloat16(h);

      hl[(t + 1) & 1][bloc][dsite] = ((const unsigned short*)&h16)[0];
      hout[(size_t)t << 10] = h16;

      // barrier WITHOUT vmcnt drain: only LDS visibility needed.
      __builtin_amdgcn_sched_barrier(0);
      asm volatile("s_waitcnt lgkmcnt(0)" ::: "memory");
      __builtin_amdgcn_sched_barrier(0);
      __builtin_amdgcn_s_barrier();
      __builtin_amdgcn_sched_barrier(0);
    }
  }
}

// ---------------------------------------------------------------------------
extern "C" void kernel_launch(void* const* d_in, const int* in_sizes, int n_in,
                              void* d_out, int out_size, void* d_ws, size_t ws_size,
                              hipStream_t stream) {
  const float* x_emb = (const float*)d_in[0];  // [16,1024,1024]
  const float* W_in  = (const float*)d_in[1];  // [1024,4096]
  const float* R     = (const float*)d_in[2];  // [4,8,128,128]
  const float* bias  = (const float*)d_in[3];  // [4,8,128]
  const float* W_prj = (const float*)d_in[4];  // [2048,1024]
  const float* b_prj = (const float*)d_in[5];  // [2048]

  char* ws = (char*)d_ws;
  bf16* xb  = (bf16*)ws;                               // 32 MB
  bf16* WiT = (bf16*)(ws + (size_t)M1 * K1 * 2);       //  8 MB (row-permuted)
  bf16* Wpb = WiT + (size_t)N1q * K1;                  //  4 MB
  bf16* H   = Wpb + (size_t)N2 * K2;                   // 32 MB
  bf16* Wx = (bf16*)d_out;  // 134 MB packed [(b*8+n)*1024+t][d*4+g]

  cast_f32_bf16<<<(M1 * K1 / 4 + 255) / 256, 256, 0, stream>>>(x_emb, xb, M1 * K1 / 4);
  transpose_cast_perm<<<dim3(N1q / 32, K1 / 32), 256, 0, stream>>>(W_in, WiT, K1, N1q);
  cast_f32_bf16<<<(N2 * K2 / 4 + 255) / 256, 256, 0, stream>>>(W_prj, Wpb, N2 * K2 / 4);

  gemm_bt<3><<<dim3(N1q / 128, M1 / 128), 256, 0, stream>>>(
      xb, WiT, (void*)Wx, bias, K1, N1q);

  lstm_mfma<<<dim3(32), 512, 0, stream>>>(Wx, R, H);

  gemm_bt<0><<<dim3(N2 / 128, M1 / 128), 256, 0, stream>>>(
      H, Wpb, d_out, b_prj, K2, N2);
}